// Round 12
// baseline (131.866 us; speedup 1.0000x reference)
//
#include <hip/hip_runtime.h>
#include <hip/hip_bf16.h>

// CausalSelfAttention: B=8 T=2048 C=126 H=6 D=21
// Round 22: QUAD-Q-BLOCK K/V REUSE. R21's double-Q (−49% tile-loads)
// cut attn 43->30.5us, confirming the L2-request-rate model after 7
// falsified scheduling theories. This round halves requests again:
// 128 queries/block (4 groups A..D) share one K/V stream, 32 MFMA per
// tile-load. Tile-loads 50688->26112. Grid (48,16), long-first.
// Groups processed in two pair-units (C/D always-mostly-active, then
// A/B) to cap live S-regs at 32. launch_bounds(256,1): ~190 VGPR
// expected, occupancy ~2 waves/SIMD (proven non-binding R5/R15).
// Tripwires: WRITE_SIZE ~6.66MB (spill), attn <= 31us (else revert).
// qkv 32-row / proj 32-row / prep unchanged.

#define B_ 8
#define T_ 2048
#define C_ 126
#define H_ 6
#define D_ 21
#define TC_ 378    // 3*C
#define KP_ 128    // padded GEMM inner dim
#define DP_ 32     // padded head dim
#define M_ 16384   // B*T
#define QSCALE 0.31481923469333463f   // (1/sqrt(21)) * log2(e)

typedef __hip_bfloat16 bf16;
typedef __bf16 bf16_t;
typedef __bf16 bf16x2 __attribute__((ext_vector_type(2)));
typedef __bf16 bf16x8 __attribute__((ext_vector_type(8)));
typedef float f32x4 __attribute__((ext_vector_type(4)));
typedef int int2v __attribute__((ext_vector_type(2)));

__device__ __forceinline__ float ldf(const bf16* p, long i) { return __bfloat162float(p[i]); }
__device__ __forceinline__ float ldf(const float* p, long i) { return p[i]; }
__device__ __forceinline__ void stf(bf16* p, long i, float v) { p[i] = __float2bfloat16(v); }
__device__ __forceinline__ void stf(float* p, long i, float v) { p[i] = v; }

// raw v_exp_f32: no libm range/fixup sequence (inputs bounded; -1e30 -> +0)
__device__ __forceinline__ float fexp2(float x) {
#if __has_builtin(__builtin_amdgcn_exp2f)
  return __builtin_amdgcn_exp2f(x);
#else
  float r; asm("v_exp_f32 %0, %1" : "=v"(r) : "v"(x)); return r;
#endif
}

__device__ __forceinline__ unsigned int ld2(const bf16* x, long i) {
  return *(const unsigned int*)((const unsigned short*)x + i);
}
__device__ __forceinline__ unsigned int ld2(const float* x, long i) {
  const float2 f = *(const float2*)(x + i);
  union { bf16_t b[2]; unsigned int u; } cv;
  cv.b[0] = (bf16_t)f.x; cv.b[1] = (bf16_t)f.y;
  return cv.u;
}

// ------------- inline dtype probe: wave 0 -> sflag (1 = bf16) -------------
__device__ __forceinline__ void probe_dtype(const void* x, int tid, int* sflag) {
  if (tid < 64) {
    const unsigned int w = ((const unsigned int*)x)[tid * 97 + 13];
    const unsigned int e = (w >> 7) & 0xFF;
    const bool bflike = (e >= 115 && e <= 131) || ((w & 0x7FFFu) == 0);
    const unsigned long long mask = __ballot(bflike);
    if (tid == 0) *sflag = (__popcll(mask) >= 40) ? 1 : 0;
  }
  __syncthreads();
}

// ------------- prep: WT_attn[384][128], WT_proj[128][128] -----------------
template <typename T>
__device__ __forceinline__ void prep_w_body(const T* __restrict__ wa,
                                            const T* __restrict__ wp,
                                            bf16_t* __restrict__ WTa,
                                            bf16_t* __restrict__ WTp) {
  const int stride = gridDim.x * blockDim.x;
  const int idx0 = blockIdx.x * blockDim.x + threadIdx.x;
  for (int i = idx0; i < 384 * KP_ + KP_ * KP_; i += stride) {
    if (i < 384 * KP_) {
      const int n = i >> 7, k = i & 127;
      WTa[i] = (k < C_ && n < TC_) ? (bf16_t)ldf(wa, (long)k * TC_ + n) : (bf16_t)0.f;
    } else {
      const int j = i - 384 * KP_;
      const int n = j >> 7, k = j & 127;
      WTp[j] = (k < C_ && n < C_) ? (bf16_t)ldf(wp, (long)k * C_ + n) : (bf16_t)0.f;
    }
  }
}

__global__ __launch_bounds__(256) void prep_w_kernel(
    const void* __restrict__ x, const void* __restrict__ wa,
    const void* __restrict__ wp, bf16_t* __restrict__ WTa,
    bf16_t* __restrict__ WTp) {
  __shared__ int sflag;
  probe_dtype(x, threadIdx.x, &sflag);
  if (sflag) prep_w_body<bf16>((const bf16*)wa, (const bf16*)wp, WTa, WTp);
  else       prep_w_body<float>((const float*)wa, (const float*)wp, WTa, WTp);
}

// ------------- qkv = x @ w_attn via MFMA, 32 rows/block -------------------
#define QS_ 40   // qbuf/kbuf d-stride (80 B, 16-aligned rows)

template <typename T>
__device__ __forceinline__ void qkv_body(
    const T* __restrict__ x, const bf16_t* __restrict__ WT,
    bf16_t* __restrict__ Qb, bf16_t* __restrict__ Kb, bf16_t* __restrict__ VT,
    bf16_t* __restrict__ xs, bf16_t* __restrict__ qbuf,
    bf16_t* __restrict__ kbuf, bf16_t* __restrict__ vbuf) {
  const int m0 = blockIdx.x * 32;
  const int tid = threadIdx.x;
  // packed x staging: 32 rows x 64 uint slots (128 cols, top 2 = pad)
  for (int i = tid; i < 32 * 64; i += 256) {
    const int row = i >> 6, cp = i & 63;
    unsigned int v = 0;
    if (cp < 63) v = ld2(x, (long)(m0 + row) * C_ + 2 * cp);
    ((unsigned int*)xs)[i] = v;
  }
  // pad init: qbuf/kbuf d=21..31 zero; vbuf d=21 ones, d=22..31 zero
  for (int i = tid; i < 6 * 32 * 11; i += 256) {
    const int h = i / 352, rem = i - h * 352, t = rem / 11, d = 21 + rem % 11;
    qbuf[(h * 32 + t) * QS_ + d] = (bf16_t)0.f;
    kbuf[(h * 32 + t) * QS_ + d] = (bf16_t)0.f;
  }
  for (int i = tid; i < 6 * 11 * 32; i += 256) {
    const int h = i / 352, rem = i - h * 352, d = 21 + rem / 32, t = rem % 32;
    vbuf[(h * 32 + d) * 32 + t] = (d == 21) ? (bf16_t)1.f : (bf16_t)0.f;
  }
  __syncthreads();

  const int wv = tid >> 6, lane = tid & 63;
  const int lr = lane & 15, quad = lane >> 4;
  const bf16_t* arU = xs + lr * KP_ + quad * 8;          // rows 0-15
  const bf16_t* arL = xs + (16 + lr) * KP_ + quad * 8;   // rows 16-31
  const bf16x8 aU0 = *(const bf16x8*)(arU);
  const bf16x8 aU1 = *(const bf16x8*)(arU + 32);
  const bf16x8 aU2 = *(const bf16x8*)(arU + 64);
  const bf16x8 aU3 = *(const bf16x8*)(arU + 96);
  const bf16x8 aL0 = *(const bf16x8*)(arL);
  const bf16x8 aL1 = *(const bf16x8*)(arL + 32);
  const bf16x8 aL2 = *(const bf16x8*)(arL + 64);
  const bf16x8 aL3 = *(const bf16x8*)(arL + 96);

  for (int nt = wv; nt < 24; nt += 4) {
    const int n0 = nt * 16;
    const bf16x8* bp = (const bf16x8*)(WT + (long)(n0 + lr) * KP_ + quad * 8);
    const bf16x8 b0 = bp[0], b1 = bp[4], b2 = bp[8], b3 = bp[12];
    f32x4 accU = {0.f, 0.f, 0.f, 0.f};
    f32x4 accL = {0.f, 0.f, 0.f, 0.f};
    accU = __builtin_amdgcn_mfma_f32_16x16x32_bf16(aU0, b0, accU, 0, 0, 0);
    accU = __builtin_amdgcn_mfma_f32_16x16x32_bf16(aU1, b1, accU, 0, 0, 0);
    accU = __builtin_amdgcn_mfma_f32_16x16x32_bf16(aU2, b2, accU, 0, 0, 0);
    accU = __builtin_amdgcn_mfma_f32_16x16x32_bf16(aU3, b3, accU, 0, 0, 0);
    accL = __builtin_amdgcn_mfma_f32_16x16x32_bf16(aL0, b0, accL, 0, 0, 0);
    accL = __builtin_amdgcn_mfma_f32_16x16x32_bf16(aL1, b1, accL, 0, 0, 0);
    accL = __builtin_amdgcn_mfma_f32_16x16x32_bf16(aL2, b2, accL, 0, 0, 0);
    accL = __builtin_amdgcn_mfma_f32_16x16x32_bf16(aL3, b3, accL, 0, 0, 0);

    const int c = n0 + lr;                 // 0..383
    if (c < TC_) {
      const int which = c / C_;
      const int cc = c - which * C_;
      const int h = cc / D_, d = cc - h * D_;
#pragma unroll
      for (int r = 0; r < 4; ++r) {
        const int tU = quad * 4 + r;       // C layout: row = quad*4 + reg
        const int tL = 16 + tU;
        if (which == 0) {
          qbuf[(h * 32 + tU) * QS_ + d] = (bf16_t)(accU[r] * QSCALE);  // incl log2e
          qbuf[(h * 32 + tL) * QS_ + d] = (bf16_t)(accL[r] * QSCALE);
        } else if (which == 1) {
          kbuf[(h * 32 + tU) * QS_ + d] = (bf16_t)accU[r];
          kbuf[(h * 32 + tL) * QS_ + d] = (bf16_t)accL[r];
        } else {
          vbuf[(h * 32 + d) * 32 + tU] = (bf16_t)accU[r];
          vbuf[(h * 32 + d) * 32 + tL] = (bf16_t)accL[r];
        }
      }
    }
  }
  __syncthreads();

  // ---- coalesced store phase ----
  const int b = m0 >> 11, t0 = m0 & 2047;
  for (int i = tid; i < 384; i += 256) {   // Q,K: 192 rows each, 64 B
    const int j = (i < 192) ? i : i - 192;
    const int h = j >> 5, t = j & 31;
    const int4* src = (const int4*)(((i < 192) ? qbuf : kbuf) + (h * 32 + t) * QS_);
    int4* dst = (int4*)((((i < 192) ? Qb : Kb)) + ((long)(b * H_ + h) * T_ + (t0 + t)) * DP_);
    dst[0] = src[0]; dst[1] = src[1]; dst[2] = src[2]; dst[3] = src[3];
  }
  for (int i = tid; i < 192; i += 256) {   // VT: 192 rows, 64 B
    const int h = i >> 5, d = i & 31;
    const int4* src = (const int4*)(vbuf + (h * 32 + d) * 32);
    int4* dst = (int4*)(VT + ((long)(b * H_ + h) * DP_ + d) * T_ + t0);
    dst[0] = src[0]; dst[1] = src[1]; dst[2] = src[2]; dst[3] = src[3];
  }
}

__global__ __launch_bounds__(256) void qkv_mfma(
    const void* __restrict__ x, const bf16_t* __restrict__ WT,
    bf16_t* __restrict__ Qb, bf16_t* __restrict__ Kb, bf16_t* __restrict__ VT) {
  __shared__ __align__(16) bf16_t xs[32 * KP_];
  __shared__ __align__(16) bf16_t qbuf[6 * 32 * QS_];
  __shared__ __align__(16) bf16_t kbuf[6 * 32 * QS_];
  __shared__ __align__(16) bf16_t vbuf[6 * 32 * 32];
  __shared__ int sflag;
  probe_dtype(x, threadIdx.x, &sflag);
  if (sflag) qkv_body<bf16>((const bf16*)x, WT, Qb, Kb, VT, xs, qbuf, kbuf, vbuf);
  else       qkv_body<float>((const float*)x, WT, Qb, Kb, VT, xs, qbuf, kbuf, vbuf);
}

// ------------- in-register P transpose helpers ----------------------------
__device__ __forceinline__ void swap32(int& a, int& b) {
#if __has_builtin(__builtin_amdgcn_permlane32_swap)
  const int2v r = __builtin_amdgcn_permlane32_swap(a, b, false, false);
  a = r[0]; b = r[1];
#else
  const int sa = __shfl_xor(a, 32, 64), sb = __shfl_xor(b, 32, 64);
  const bool hi = (threadIdx.x & 32) != 0;
  a = hi ? sb : a;
  b = hi ? b : sa;
#endif
}

__device__ __forceinline__ void swap16(int& a, int& b) {
#if __has_builtin(__builtin_amdgcn_permlane16_swap)
  const int2v r = __builtin_amdgcn_permlane16_swap(a, b, false, false);
  a = r[0]; b = r[1];
#else
  const int sa = __shfl_xor(a, 16, 64), sb = __shfl_xor(b, 16, 64);
  const bool odd = (threadIdx.x & 16) != 0;
  a = odd ? sb : a;
  b = odd ? b : sa;
#endif
}

__device__ __forceinline__ int pkbf(float x, float y) {
  union { bf16x2 h; int i; } u;
  u.h[0] = (bf16_t)x; u.h[1] = (bf16_t)y;
  return u.i;
}

// g1 = exp'd S^T for keys quad*4+r (tile keys 0-15), g2 = keys 16+quad*4+r
__device__ __forceinline__ bf16x8 build_frag(const f32x4 g1, const f32x4 g2) {
  int a1 = pkbf(g1[0], g1[1]);
  int b1 = pkbf(g1[2], g1[3]);
  int a2 = pkbf(g2[0], g2[1]);
  int b2 = pkbf(g2[2], g2[3]);
  swap32(a1, a2); swap32(b1, b2);
  swap16(a1, a2); swap16(b1, b2);
  union { int i[4]; bf16x8 v; } u;
  u.i[0] = a1; u.i[1] = b1; u.i[2] = a2; u.i[3] = b2;
  return u.v;
}

// diagonal mask in S^T orientation
__device__ __forceinline__ void diag_mask(f32x4& s00, f32x4& s10, f32x4& s11,
                                          int mq, int lr) {
#pragma unroll
  for (int r = 0; r < 4; ++r) {
    if (mq + r > lr) { s00[r] = -1e30f; s11[r] = -1e30f; }
    s10[r] = -1e30f;
  }
}

__device__ __forceinline__ void exp4(f32x4& a, f32x4& b, f32x4& c, f32x4& d) {
#pragma unroll
  for (int r = 0; r < 4; ++r) {
    a[r] = fexp2(a[r]); b[r] = fexp2(b[r]);
    c[r] = fexp2(c[r]); d[r] = fexp2(d[r]);
  }
}

// ------------- MFMA causal flash attention, quad-Q-block ------------------
// grid (48, 16): x = bh, y -> qb = 15-y (long blocks first). Block owns
// 128 queries q0=qb*128: groups A/B/C/D at +0/+32/+64/+96, sharing one
// K/V stream. Wave wv owns tiles {wv, wv+4, ...} <= d3=4qb+3. Group g
// active iff t <= 4qb+g (uniform); diag for g at t == 4qb+g. Per tile:
// 2 K loads -> S-MFMA pair(C,D) -> 2 V loads -> mask/exp/frag/PV(C,D)
// -> [if t<=d1] same for pair(A,B). 32 MFMA per tile-load. Four-pass
// merge over same 17KB LDS. Native exp2; setprio on MFMA clusters.
__global__ __launch_bounds__(256, 1) void attn_mfma(
    const bf16_t* __restrict__ Qb, const bf16_t* __restrict__ Kb,
    const bf16_t* __restrict__ VT, bf16_t* __restrict__ ATTp) {
  __shared__ __align__(16) float smem[4352];      // 17KB merge buffer
  const int bh = blockIdx.x;
  const int qb = 15 - blockIdx.y;                 // long blocks first
  const int d0 = 4 * qb, d1 = d0 + 1, d2 = d0 + 2, d3 = d0 + 3;
  const int q0 = qb * 128;
  const int tid = threadIdx.x;
  const int wv = tid >> 6, lane = tid & 63;
  const int lr = lane & 15, quad = lane >> 4;
  const int mq = quad * 4;

  const bf16_t* Qbh = Qb + (long)bh * T_ * DP_;
  const bf16_t* Kbh = Kb + (long)bh * T_ * DP_;
  const bf16_t* VTbh = VT + (long)bh * DP_ * T_;

  const bf16x8 qA0 = *(const bf16x8*)(Qbh + (long)(q0 + lr) * DP_ + quad * 8);
  const bf16x8 qA1 = *(const bf16x8*)(Qbh + (long)(q0 + 16 + lr) * DP_ + quad * 8);
  const bf16x8 qB0 = *(const bf16x8*)(Qbh + (long)(q0 + 32 + lr) * DP_ + quad * 8);
  const bf16x8 qB1 = *(const bf16x8*)(Qbh + (long)(q0 + 48 + lr) * DP_ + quad * 8);
  const bf16x8 qC0 = *(const bf16x8*)(Qbh + (long)(q0 + 64 + lr) * DP_ + quad * 8);
  const bf16x8 qC1 = *(const bf16x8*)(Qbh + (long)(q0 + 80 + lr) * DP_ + quad * 8);
  const bf16x8 qD0 = *(const bf16x8*)(Qbh + (long)(q0 + 96 + lr) * DP_ + quad * 8);
  const bf16x8 qD1 = *(const bf16x8*)(Qbh + (long)(q0 + 112 + lr) * DP_ + quad * 8);

  f32x4 oA00 = {0.f,0.f,0.f,0.f}, oA01 = {0.f,0.f,0.f,0.f};
  f32x4 oA10 = {0.f,0.f,0.f,0.f}, oA11 = {0.f,0.f,0.f,0.f};
  f32x4 oB00 = {0.f,0.f,0.f,0.f}, oB01 = {0.f,0.f,0.f,0.f};
  f32x4 oB10 = {0.f,0.f,0.f,0.f}, oB11 = {0.f,0.f,0.f,0.f};
  f32x4 oC00 = {0.f,0.f,0.f,0.f}, oC01 = {0.f,0.f,0.f,0.f};
  f32x4 oC10 = {0.f,0.f,0.f,0.f}, oC11 = {0.f,0.f,0.f,0.f};
  f32x4 oD00 = {0.f,0.f,0.f,0.f}, oD01 = {0.f,0.f,0.f,0.f};
  f32x4 oD10 = {0.f,0.f,0.f,0.f}, oD11 = {0.f,0.f,0.f,0.f};

  for (int t = wv; t <= d3; t += 4) {
    const int kb = t * 32;
    const bf16x8 k0 = *(const bf16x8*)(Kbh + (long)(kb + lr) * DP_ + quad * 8);
    const bf16x8 k1 = *(const bf16x8*)(Kbh + (long)(kb + 16 + lr) * DP_ + quad * 8);

    // ---- pair unit 1: groups C (t<=d2), D (always) ----
    f32x4 sC00 = {0.f,0.f,0.f,0.f}, sC01 = {0.f,0.f,0.f,0.f};
    f32x4 sC10 = {0.f,0.f,0.f,0.f}, sC11 = {0.f,0.f,0.f,0.f};
    f32x4 sD00 = {0.f,0.f,0.f,0.f}, sD01 = {0.f,0.f,0.f,0.f};
    f32x4 sD10 = {0.f,0.f,0.f,0.f}, sD11 = {0.f,0.f,0.f,0.f};
    __builtin_amdgcn_s_setprio(1);
    if (t <= d2) {
      sC00 = __builtin_amdgcn_mfma_f32_16x16x32_bf16(k0, qC0, sC00, 0, 0, 0);
      sC01 = __builtin_amdgcn_mfma_f32_16x16x32_bf16(k0, qC1, sC01, 0, 0, 0);
      sC10 = __builtin_amdgcn_mfma_f32_16x16x32_bf16(k1, qC0, sC10, 0, 0, 0);
      sC11 = __builtin_amdgcn_mfma_f32_16x16x32_bf16(k1, qC1, sC11, 0, 0, 0);
    }
    sD00 = __builtin_amdgcn_mfma_f32_16x16x32_bf16(k0, qD0, sD00, 0, 0, 0);
    sD01 = __builtin_amdgcn_mfma_f32_16x16x32_bf16(k0, qD1, sD01, 0, 0, 0);
    sD10 = __builtin_amdgcn_mfma_f32_16x16x32_bf16(k1, qD0, sD10, 0, 0, 0);
    sD11 = __builtin_amdgcn_mfma_f32_16x16x32_bf16(k1, qD1, sD11, 0, 0, 0);
    __builtin_amdgcn_s_setprio(0);

    // V loads after first S cluster: first use is PV
    const bf16x8 v0 = *(const bf16x8*)(VTbh + (long)lr * T_ + kb + quad * 8);
    const bf16x8 v1 = *(const bf16x8*)(VTbh + (long)(16 + lr) * T_ + kb + quad * 8);

    if (t == d2) diag_mask(sC00, sC10, sC11, mq, lr);
    if (t == d3) diag_mask(sD00, sD10, sD11, mq, lr);
    if (t <= d2) exp4(sC00, sC01, sC10, sC11);
    exp4(sD00, sD01, sD10, sD11);

    __builtin_amdgcn_s_setprio(1);
    if (t <= d2) {
      const bf16x8 pC0 = build_frag(sC00, sC10);
      const bf16x8 pC1 = build_frag(sC01, sC11);
      oC00 = __builtin_amdgcn_mfma_f32_16x16x32_bf16(pC0, v0, oC00, 0, 0, 0);
      oC01 = __builtin_amdgcn_mfma_f32_16x16x32_bf16(pC0, v1, oC01, 0, 0, 0);
      oC10 = __builtin_amdgcn_mfma_f32_16x16x32_bf16(pC1, v0, oC10, 0, 0, 0);
      oC11 = __builtin_amdgcn_mfma_f32_16x16x32_bf16(pC1, v1, oC11, 0, 0, 0);
    }
    {
      const bf16x8 pD0 = build_frag(sD00, sD10);
      const bf16x8 pD1 = build_frag(sD01, sD11);
      oD00 = __builtin_amdgcn_mfma_f32_16x16x32_bf16(pD0, v0, oD00, 0, 0, 0);
      oD01 = __builtin_amdgcn_mfma_f32_16x16x32_bf16(pD0, v1, oD01, 0, 0, 0);
      oD10 = __builtin_amdgcn_mfma_f32_16x16x32_bf16(pD1, v0, oD10, 0, 0, 0);
      oD11 = __builtin_amdgcn_mfma_f32_16x16x32_bf16(pD1, v1, oD11, 0, 0, 0);
    }
    __builtin_amdgcn_s_setprio(0);

    // ---- pair unit 2: groups A (t<=d0), B (t<=d1) ----
    if (t <= d1) {
      f32x4 sA00 = {0.f,0.f,0.f,0.f}, sA01 = {0.f,0.f,0.f,0.f};
      f32x4 sA10 = {0.f,0.f,0.f,0.f}, sA11 = {0.f,0.f,0.f,0.f};
      f32x4 sB00 = {0.f,0.f,0.f,0.f}, sB01 = {0.f,0.f,0.f,0.f};
      f32x4 sB10 = {0.f,0.f,0.f,0.f}, sB11 = {0.f,0.f,0.f,0.f};
      __builtin_amdgcn_s_setprio(1);
      if (t <= d0) {
        sA00 = __builtin_amdgcn_mfma_f32_16x16x32_bf16(k0, qA0, sA00, 0, 0, 0);
        sA01 = __builtin_amdgcn_mfma_f32_16x16x32_bf16(k0, qA1, sA01, 0, 0, 0);
        sA10 = __builtin_amdgcn_mfma_f32_16x16x32_bf16(k1, qA0, sA10, 0, 0, 0);
        sA11 = __builtin_amdgcn_mfma_f32_16x16x32_bf16(k1, qA1, sA11, 0, 0, 0);
      }
      sB00 = __builtin_amdgcn_mfma_f32_16x16x32_bf16(k0, qB0, sB00, 0, 0, 0);
      sB01 = __builtin_amdgcn_mfma_f32_16x16x32_bf16(k0, qB1, sB01, 0, 0, 0);
      sB10 = __builtin_amdgcn_mfma_f32_16x16x32_bf16(k1, qB0, sB10, 0, 0, 0);
      sB11 = __builtin_amdgcn_mfma_f32_16x16x32_bf16(k1, qB1, sB11, 0, 0, 0);
      __builtin_amdgcn_s_setprio(0);

      if (t == d0) diag_mask(sA00, sA10, sA11, mq, lr);
      if (t == d1) diag_mask(sB00, sB10, sB11, mq, lr);
      if (t <= d0) exp4(sA00, sA01, sA10, sA11);
      exp4(sB00, sB01, sB10, sB11);

      __builtin_amdgcn_s_setprio(1);
      if (t <= d0) {
        const bf16x8 pA0 = build_frag(sA00, sA10);
        const bf16x8 pA1 = build_frag(sA01, sA11);
        oA00 = __builtin_amdgcn_mfma_f32_16x16x32_bf16(pA0, v0, oA00, 0, 0, 0);
        oA01 = __builtin_amdgcn_mfma_f32_16x16x32_bf16(pA0, v1, oA01, 0, 0, 0);
        oA10 = __builtin_amdgcn_mfma_f32_16x16x32_bf16(pA1, v0, oA10, 0, 0, 0);
        oA11 = __builtin_amdgcn_mfma_f32_16x16x32_bf16(pA1, v1, oA11, 0, 0, 0);
      }
      {
        const bf16x8 pB0 = build_frag(sB00, sB10);
        const bf16x8 pB1 = build_frag(sB01, sB11);
        oB00 = __builtin_amdgcn_mfma_f32_16x16x32_bf16(pB0, v0, oB00, 0, 0, 0);
        oB01 = __builtin_amdgcn_mfma_f32_16x16x32_bf16(pB0, v1, oB01, 0, 0, 0);
        oB10 = __builtin_amdgcn_mfma_f32_16x16x32_bf16(pB1, v0, oB10, 0, 0, 0);
        oB11 = __builtin_amdgcn_mfma_f32_16x16x32_bf16(pB1, v1, oB11, 0, 0, 0);
      }
      __builtin_amdgcn_s_setprio(0);
    }
  }

  // ---- four-pass merge: partials are additive (no-max softmax) ----
  const int b = bh / H_, h = bh - b * H_;

  auto merge_pass = [&](const f32x4& m00, const f32x4& m01,
                        const f32x4& m10, const f32x4& m11, int qoff) {
    __syncthreads();
    {
      float* my = smem + (wv * 64 + lane) * 17;   // stride 17: conflict-free
#pragma unroll
      for (int j = 0; j < 4; ++j) {
        my[j]      = m00[j];
        my[4 + j]  = m01[j];
        my[8 + j]  = m10[j];
        my[12 + j] = m11[j];
      }
    }
    __syncthreads();
    if (wv == 0) {
      float tot[16];
#pragma unroll
      for (int j = 0; j < 16; ++j)
        tot[j] = smem[lane * 17 + j] + smem[(64 + lane) * 17 + j] +
                 smem[(128 + lane) * 17 + j] + smem[(192 + lane) * 17 + j];
#pragma unroll
      for (int r = 0; r < 4; ++r) {
        const float rl0 = 1.f / __shfl(tot[4 + r],  (lane & 48) + 5, 64);
        const float rl1 = 1.f / __shfl(tot[12 + r], (lane & 48) + 5, 64);
        const int qA = q0 + qoff + mq + r, qB2 = qA + 16;
        bf16_t* opA = ATTp + (long)(b * T_ + qA) * KP_ + h * D_;
        bf16_t* opB = ATTp + (long)(b * T_ + qB2) * KP_ + h * D_;
        opA[lr] = (bf16_t)(tot[r] * rl0);
        opB[lr] = (bf16_t)(tot[8 + r] * rl1);
        if (lr < 5) {
          opA[16 + lr] = (bf16_t)(tot[4 + r] * rl0);
          opB[16 + lr] = (bf16_t)(tot[12 + r] * rl1);
        }
      }
    }
  };

  merge_pass(oA00, oA01, oA10, oA11, 0);
  merge_pass(oB00, oB01, oB10, oB11, 32);
  merge_pass(oC00, oC01, oC10, oC11, 64);
  merge_pass(oD00, oD01, oD10, oD11, 96);
}

// ------------- out = ATT @ w_proj via MFMA, 32 rows/block -----------------
__global__ __launch_bounds__(256) void proj_mfma(
    const void* __restrict__ x, const bf16_t* __restrict__ ATTp,
    const bf16_t* __restrict__ WT, void* __restrict__ out) {
  __shared__ int sflag;
  probe_dtype(x, threadIdx.x, &sflag);
  const int isbf = sflag;

  const int m0 = blockIdx.x * 32;
  const int tid = threadIdx.x;
  const int wv = tid >> 6, lane = tid & 63;
  const int lr = lane & 15, quad = lane >> 4;

  const bf16x8* apU = (const bf16x8*)(ATTp + (long)(m0 + lr) * KP_ + quad * 8);
  const bf16x8* apL = (const bf16x8*)(ATTp + (long)(m0 + 16 + lr) * KP_ + quad * 8);
  const bf16x8 aU0 = apU[0], aU1 = apU[4], aU2 = apU[8], aU3 = apU[12];
  const bf16x8 aL0 = apL[0], aL1 = apL[4], aL2 = apL[8], aL3 = apL[12];

  for (int nt = wv; nt < 8; nt += 4) {
    const int n0 = nt * 16;
    const bf16x8* bp = (const bf16x8*)(WT + (long)(n0 + lr) * KP_ + quad * 8);
    const bf16x8 b0 = bp[0], b1 = bp[4], b2 = bp[8], b3 = bp[12];
    f32x4 accU = {0.f, 0.f, 0.f, 0.f};
    f32x4 accL = {0.f, 0.f, 0.f, 0.f};
    accU = __builtin_amdgcn_mfma_f32_16x16x32_bf16(aU0, b0, accU, 0, 0, 0);
    accU = __builtin_amdgcn_mfma_f32_16x16x32_bf16(aU1, b1, accU, 0, 0, 0);
    accU = __builtin_amdgcn_mfma_f32_16x16x32_bf16(aU2, b2, accU, 0, 0, 0);
    accU = __builtin_amdgcn_mfma_f32_16x16x32_bf16(aU3, b3, accU, 0, 0, 0);
    accL = __builtin_amdgcn_mfma_f32_16x16x32_bf16(aL0, b0, accL, 0, 0, 0);
    accL = __builtin_amdgcn_mfma_f32_16x16x32_bf16(aL1, b1, accL, 0, 0, 0);
    accL = __builtin_amdgcn_mfma_f32_16x16x32_bf16(aL2, b2, accL, 0, 0, 0);
    accL = __builtin_amdgcn_mfma_f32_16x16x32_bf16(aL3, b3, accL, 0, 0, 0);

    const int c = n0 + lr;
    if (c < C_) {
#pragma unroll
      for (int r = 0; r < 4; ++r) {
        const int mU = m0 + quad * 4 + r;
        const int mL = mU + 16;
        if (isbf) {
          stf((bf16*)out,  (long)mU * C_ + c, accU[r]);
          stf((bf16*)out,  (long)mL * C_ + c, accL[r]);
        } else {
          stf((float*)out, (long)mU * C_ + c, accU[r]);
          stf((float*)out, (long)mL * C_ + c, accL[r]);
        }
      }
    }
  }
}

extern "C" void kernel_launch(void* const* d_in, const int* in_sizes, int n_in,
                              void* d_out, int out_size, void* d_ws, size_t ws_size,
                              hipStream_t stream) {
  const void* x      = d_in[0];
  const void* w_attn = d_in[1];
  const void* w_proj = d_in[2];

  char* base = (char*)d_ws;
  const long QKV = (long)48 * T_ * DP_;                    // 3,145,728 bf16 each
  bf16_t* Qb = (bf16_t*)(base + 256);
  bf16_t* Kb = Qb + QKV;
  bf16_t* VT = Kb + QKV;                                   // [bh][32][T]
  bf16_t* WTa  = VT + QKV;                                 // 384*128
  bf16_t* WTp  = WTa + 384 * KP_;                          // 128*128
  bf16_t* ATTp = WTp + KP_ * KP_;                          // 16384*128

  prep_w_kernel<<<64, 256, 0, stream>>>(x, w_attn, w_proj, WTa, WTp);
  qkv_mfma<<<M_ / 32, 256, 0, stream>>>(x, WTa, Qb, Kb, VT);
  attn_mfma<<<dim3(48, 16), 256, 0, stream>>>(Qb, Kb, VT, ATTp);
  proj_mfma<<<M_ / 32, 256, 0, stream>>>(x, ATTp, WTp, d_out);
}

// Round 13
// 115.864 us; speedup vs baseline: 1.1381x; 1.1381x over previous
//
#include <hip/hip_runtime.h>
#include <hip/hip_bf16.h>

// CausalSelfAttention: B=8 T=2048 C=126 H=6 D=21
// Round 23: REVERT to R21 (best measured: 116.7us total, attn 30.5us).
// R22's quad-Q hit the register wall: VGPR 112 -> occupancy 15.5% ->
// attn 44.7us (latency re-exposed). Double-Q (2 groups, VGPR ~<=100,
// launch_bounds(256,2)) is the optimum on the K/V-reuse axis.
// Only change vs R21: prep_w grid 64->256 blocks (grid-strided; more
// parallelism for its 65K elements). Non-attn remainder is 86+-1us
// across all rounds (one 268MB harness re-poison fill ~43us + small
// near-floor kernels) — structural.

#define B_ 8
#define T_ 2048
#define C_ 126
#define H_ 6
#define D_ 21
#define TC_ 378    // 3*C
#define KP_ 128    // padded GEMM inner dim
#define DP_ 32     // padded head dim
#define M_ 16384   // B*T
#define QSCALE 0.31481923469333463f   // (1/sqrt(21)) * log2(e)

typedef __hip_bfloat16 bf16;
typedef __bf16 bf16_t;
typedef __bf16 bf16x2 __attribute__((ext_vector_type(2)));
typedef __bf16 bf16x8 __attribute__((ext_vector_type(8)));
typedef float f32x4 __attribute__((ext_vector_type(4)));
typedef int int2v __attribute__((ext_vector_type(2)));

__device__ __forceinline__ float ldf(const bf16* p, long i) { return __bfloat162float(p[i]); }
__device__ __forceinline__ float ldf(const float* p, long i) { return p[i]; }
__device__ __forceinline__ void stf(bf16* p, long i, float v) { p[i] = __float2bfloat16(v); }
__device__ __forceinline__ void stf(float* p, long i, float v) { p[i] = v; }

// raw v_exp_f32: no libm range/fixup sequence (inputs bounded; -1e30 -> +0)
__device__ __forceinline__ float fexp2(float x) {
#if __has_builtin(__builtin_amdgcn_exp2f)
  return __builtin_amdgcn_exp2f(x);
#else
  float r; asm("v_exp_f32 %0, %1" : "=v"(r) : "v"(x)); return r;
#endif
}

__device__ __forceinline__ unsigned int ld2(const bf16* x, long i) {
  return *(const unsigned int*)((const unsigned short*)x + i);
}
__device__ __forceinline__ unsigned int ld2(const float* x, long i) {
  const float2 f = *(const float2*)(x + i);
  union { bf16_t b[2]; unsigned int u; } cv;
  cv.b[0] = (bf16_t)f.x; cv.b[1] = (bf16_t)f.y;
  return cv.u;
}

// ------------- inline dtype probe: wave 0 -> sflag (1 = bf16) -------------
__device__ __forceinline__ void probe_dtype(const void* x, int tid, int* sflag) {
  if (tid < 64) {
    const unsigned int w = ((const unsigned int*)x)[tid * 97 + 13];
    const unsigned int e = (w >> 7) & 0xFF;
    const bool bflike = (e >= 115 && e <= 131) || ((w & 0x7FFFu) == 0);
    const unsigned long long mask = __ballot(bflike);
    if (tid == 0) *sflag = (__popcll(mask) >= 40) ? 1 : 0;
  }
  __syncthreads();
}

// ------------- prep: WT_attn[384][128], WT_proj[128][128] -----------------
template <typename T>
__device__ __forceinline__ void prep_w_body(const T* __restrict__ wa,
                                            const T* __restrict__ wp,
                                            bf16_t* __restrict__ WTa,
                                            bf16_t* __restrict__ WTp) {
  const int stride = gridDim.x * blockDim.x;
  const int idx0 = blockIdx.x * blockDim.x + threadIdx.x;
  for (int i = idx0; i < 384 * KP_ + KP_ * KP_; i += stride) {
    if (i < 384 * KP_) {
      const int n = i >> 7, k = i & 127;
      WTa[i] = (k < C_ && n < TC_) ? (bf16_t)ldf(wa, (long)k * TC_ + n) : (bf16_t)0.f;
    } else {
      const int j = i - 384 * KP_;
      const int n = j >> 7, k = j & 127;
      WTp[j] = (k < C_ && n < C_) ? (bf16_t)ldf(wp, (long)k * C_ + n) : (bf16_t)0.f;
    }
  }
}

__global__ __launch_bounds__(256) void prep_w_kernel(
    const void* __restrict__ x, const void* __restrict__ wa,
    const void* __restrict__ wp, bf16_t* __restrict__ WTa,
    bf16_t* __restrict__ WTp) {
  __shared__ int sflag;
  probe_dtype(x, threadIdx.x, &sflag);
  if (sflag) prep_w_body<bf16>((const bf16*)wa, (const bf16*)wp, WTa, WTp);
  else       prep_w_body<float>((const float*)wa, (const float*)wp, WTa, WTp);
}

// ------------- qkv = x @ w_attn via MFMA, 32 rows/block -------------------
#define QS_ 40   // qbuf/kbuf d-stride (80 B, 16-aligned rows)

template <typename T>
__device__ __forceinline__ void qkv_body(
    const T* __restrict__ x, const bf16_t* __restrict__ WT,
    bf16_t* __restrict__ Qb, bf16_t* __restrict__ Kb, bf16_t* __restrict__ VT,
    bf16_t* __restrict__ xs, bf16_t* __restrict__ qbuf,
    bf16_t* __restrict__ kbuf, bf16_t* __restrict__ vbuf) {
  const int m0 = blockIdx.x * 32;
  const int tid = threadIdx.x;
  // packed x staging: 32 rows x 64 uint slots (128 cols, top 2 = pad)
  for (int i = tid; i < 32 * 64; i += 256) {
    const int row = i >> 6, cp = i & 63;
    unsigned int v = 0;
    if (cp < 63) v = ld2(x, (long)(m0 + row) * C_ + 2 * cp);
    ((unsigned int*)xs)[i] = v;
  }
  // pad init: qbuf/kbuf d=21..31 zero; vbuf d=21 ones, d=22..31 zero
  for (int i = tid; i < 6 * 32 * 11; i += 256) {
    const int h = i / 352, rem = i - h * 352, t = rem / 11, d = 21 + rem % 11;
    qbuf[(h * 32 + t) * QS_ + d] = (bf16_t)0.f;
    kbuf[(h * 32 + t) * QS_ + d] = (bf16_t)0.f;
  }
  for (int i = tid; i < 6 * 11 * 32; i += 256) {
    const int h = i / 352, rem = i - h * 352, d = 21 + rem / 32, t = rem % 32;
    vbuf[(h * 32 + d) * 32 + t] = (d == 21) ? (bf16_t)1.f : (bf16_t)0.f;
  }
  __syncthreads();

  const int wv = tid >> 6, lane = tid & 63;
  const int lr = lane & 15, quad = lane >> 4;
  const bf16_t* arU = xs + lr * KP_ + quad * 8;          // rows 0-15
  const bf16_t* arL = xs + (16 + lr) * KP_ + quad * 8;   // rows 16-31
  const bf16x8 aU0 = *(const bf16x8*)(arU);
  const bf16x8 aU1 = *(const bf16x8*)(arU + 32);
  const bf16x8 aU2 = *(const bf16x8*)(arU + 64);
  const bf16x8 aU3 = *(const bf16x8*)(arU + 96);
  const bf16x8 aL0 = *(const bf16x8*)(arL);
  const bf16x8 aL1 = *(const bf16x8*)(arL + 32);
  const bf16x8 aL2 = *(const bf16x8*)(arL + 64);
  const bf16x8 aL3 = *(const bf16x8*)(arL + 96);

  for (int nt = wv; nt < 24; nt += 4) {
    const int n0 = nt * 16;
    const bf16x8* bp = (const bf16x8*)(WT + (long)(n0 + lr) * KP_ + quad * 8);
    const bf16x8 b0 = bp[0], b1 = bp[4], b2 = bp[8], b3 = bp[12];
    f32x4 accU = {0.f, 0.f, 0.f, 0.f};
    f32x4 accL = {0.f, 0.f, 0.f, 0.f};
    accU = __builtin_amdgcn_mfma_f32_16x16x32_bf16(aU0, b0, accU, 0, 0, 0);
    accU = __builtin_amdgcn_mfma_f32_16x16x32_bf16(aU1, b1, accU, 0, 0, 0);
    accU = __builtin_amdgcn_mfma_f32_16x16x32_bf16(aU2, b2, accU, 0, 0, 0);
    accU = __builtin_amdgcn_mfma_f32_16x16x32_bf16(aU3, b3, accU, 0, 0, 0);
    accL = __builtin_amdgcn_mfma_f32_16x16x32_bf16(aL0, b0, accL, 0, 0, 0);
    accL = __builtin_amdgcn_mfma_f32_16x16x32_bf16(aL1, b1, accL, 0, 0, 0);
    accL = __builtin_amdgcn_mfma_f32_16x16x32_bf16(aL2, b2, accL, 0, 0, 0);
    accL = __builtin_amdgcn_mfma_f32_16x16x32_bf16(aL3, b3, accL, 0, 0, 0);

    const int c = n0 + lr;                 // 0..383
    if (c < TC_) {
      const int which = c / C_;
      const int cc = c - which * C_;
      const int h = cc / D_, d = cc - h * D_;
#pragma unroll
      for (int r = 0; r < 4; ++r) {
        const int tU = quad * 4 + r;       // C layout: row = quad*4 + reg
        const int tL = 16 + tU;
        if (which == 0) {
          qbuf[(h * 32 + tU) * QS_ + d] = (bf16_t)(accU[r] * QSCALE);  // incl log2e
          qbuf[(h * 32 + tL) * QS_ + d] = (bf16_t)(accL[r] * QSCALE);
        } else if (which == 1) {
          kbuf[(h * 32 + tU) * QS_ + d] = (bf16_t)accU[r];
          kbuf[(h * 32 + tL) * QS_ + d] = (bf16_t)accL[r];
        } else {
          vbuf[(h * 32 + d) * 32 + tU] = (bf16_t)accU[r];
          vbuf[(h * 32 + d) * 32 + tL] = (bf16_t)accL[r];
        }
      }
    }
  }
  __syncthreads();

  // ---- coalesced store phase ----
  const int b = m0 >> 11, t0 = m0 & 2047;
  for (int i = tid; i < 384; i += 256) {   // Q,K: 192 rows each, 64 B
    const int j = (i < 192) ? i : i - 192;
    const int h = j >> 5, t = j & 31;
    const int4* src = (const int4*)(((i < 192) ? qbuf : kbuf) + (h * 32 + t) * QS_);
    int4* dst = (int4*)((((i < 192) ? Qb : Kb)) + ((long)(b * H_ + h) * T_ + (t0 + t)) * DP_);
    dst[0] = src[0]; dst[1] = src[1]; dst[2] = src[2]; dst[3] = src[3];
  }
  for (int i = tid; i < 192; i += 256) {   // VT: 192 rows, 64 B
    const int h = i >> 5, d = i & 31;
    const int4* src = (const int4*)(vbuf + (h * 32 + d) * 32);
    int4* dst = (int4*)(VT + ((long)(b * H_ + h) * DP_ + d) * T_ + t0);
    dst[0] = src[0]; dst[1] = src[1]; dst[2] = src[2]; dst[3] = src[3];
  }
}

__global__ __launch_bounds__(256) void qkv_mfma(
    const void* __restrict__ x, const bf16_t* __restrict__ WT,
    bf16_t* __restrict__ Qb, bf16_t* __restrict__ Kb, bf16_t* __restrict__ VT) {
  __shared__ __align__(16) bf16_t xs[32 * KP_];
  __shared__ __align__(16) bf16_t qbuf[6 * 32 * QS_];
  __shared__ __align__(16) bf16_t kbuf[6 * 32 * QS_];
  __shared__ __align__(16) bf16_t vbuf[6 * 32 * 32];
  __shared__ int sflag;
  probe_dtype(x, threadIdx.x, &sflag);
  if (sflag) qkv_body<bf16>((const bf16*)x, WT, Qb, Kb, VT, xs, qbuf, kbuf, vbuf);
  else       qkv_body<float>((const float*)x, WT, Qb, Kb, VT, xs, qbuf, kbuf, vbuf);
}

// ------------- in-register P transpose helpers ----------------------------
__device__ __forceinline__ void swap32(int& a, int& b) {
#if __has_builtin(__builtin_amdgcn_permlane32_swap)
  const int2v r = __builtin_amdgcn_permlane32_swap(a, b, false, false);
  a = r[0]; b = r[1];
#else
  const int sa = __shfl_xor(a, 32, 64), sb = __shfl_xor(b, 32, 64);
  const bool hi = (threadIdx.x & 32) != 0;
  a = hi ? sb : a;
  b = hi ? b : sa;
#endif
}

__device__ __forceinline__ void swap16(int& a, int& b) {
#if __has_builtin(__builtin_amdgcn_permlane16_swap)
  const int2v r = __builtin_amdgcn_permlane16_swap(a, b, false, false);
  a = r[0]; b = r[1];
#else
  const int sa = __shfl_xor(a, 16, 64), sb = __shfl_xor(b, 16, 64);
  const bool odd = (threadIdx.x & 16) != 0;
  a = odd ? sb : a;
  b = odd ? b : sa;
#endif
}

__device__ __forceinline__ int pkbf(float x, float y) {
  union { bf16x2 h; int i; } u;
  u.h[0] = (bf16_t)x; u.h[1] = (bf16_t)y;
  return u.i;
}

// g1 = exp'd S^T for keys quad*4+r (tile keys 0-15), g2 = keys 16+quad*4+r
__device__ __forceinline__ bf16x8 build_frag(const f32x4 g1, const f32x4 g2) {
  int a1 = pkbf(g1[0], g1[1]);
  int b1 = pkbf(g1[2], g1[3]);
  int a2 = pkbf(g2[0], g2[1]);
  int b2 = pkbf(g2[2], g2[3]);
  swap32(a1, a2); swap32(b1, b2);
  swap16(a1, a2); swap16(b1, b2);
  union { int i[4]; bf16x8 v; } u;
  u.i[0] = a1; u.i[1] = b1; u.i[2] = a2; u.i[3] = b2;
  return u.v;
}

// ------------- MFMA causal flash attention, double-Q-block ----------------
// grid (48, 32): x = bh (same-bh -> same XCD since 48%8==0), y -> qb =
// 31-y (long blocks first). Block owns 64 queries q0=qb*64: group A =
// q0..q0+31, group B = q0+32..q0+63, sharing one K/V stream. Wave wv
// owns tiles {wv, wv+4, ...} <= d1=2qb+1. Per tile: 2 K loads ->
// 4+4 S-MFMA (A skipped iff t==d1) -> 2 V loads -> mask/exp/frags ->
// 4+4 PV-MFMA. 16 MFMA per tile-load. Diag: t==d0 masks A, t==d1
// masks B. Two-pass merge over same 17KB LDS. Native exp2; setprio.
__global__ __launch_bounds__(256, 2) void attn_mfma(
    const bf16_t* __restrict__ Qb, const bf16_t* __restrict__ Kb,
    const bf16_t* __restrict__ VT, bf16_t* __restrict__ ATTp) {
  __shared__ __align__(16) float smem[4352];      // 17KB merge buffer
  const int bh = blockIdx.x;
  const int qb = 31 - blockIdx.y;                 // long blocks first
  const int d0 = 2 * qb, d1 = d0 + 1;
  const int q0 = qb * 64;
  const int tid = threadIdx.x;
  const int wv = tid >> 6, lane = tid & 63;
  const int lr = lane & 15, quad = lane >> 4;
  const int mq = quad * 4;

  const bf16_t* Qbh = Qb + (long)bh * T_ * DP_;
  const bf16_t* Kbh = Kb + (long)bh * T_ * DP_;
  const bf16_t* VTbh = VT + (long)bh * DP_ * T_;

  const bf16x8 qA0 = *(const bf16x8*)(Qbh + (long)(q0 + lr) * DP_ + quad * 8);
  const bf16x8 qA1 = *(const bf16x8*)(Qbh + (long)(q0 + 16 + lr) * DP_ + quad * 8);
  const bf16x8 qB0 = *(const bf16x8*)(Qbh + (long)(q0 + 32 + lr) * DP_ + quad * 8);
  const bf16x8 qB1 = *(const bf16x8*)(Qbh + (long)(q0 + 48 + lr) * DP_ + quad * 8);

  f32x4 oA00 = {0.f,0.f,0.f,0.f}, oA01 = {0.f,0.f,0.f,0.f};
  f32x4 oA10 = {0.f,0.f,0.f,0.f}, oA11 = {0.f,0.f,0.f,0.f};
  f32x4 oB00 = {0.f,0.f,0.f,0.f}, oB01 = {0.f,0.f,0.f,0.f};
  f32x4 oB10 = {0.f,0.f,0.f,0.f}, oB11 = {0.f,0.f,0.f,0.f};

  for (int t = wv; t <= d1; t += 4) {
    const int kb = t * 32;
    const bool do0 = (t <= d0);                   // group A active (uniform)
    const bf16x8 k0 = *(const bf16x8*)(Kbh + (long)(kb + lr) * DP_ + quad * 8);
    const bf16x8 k1 = *(const bf16x8*)(Kbh + (long)(kb + 16 + lr) * DP_ + quad * 8);

    // swapped operands: S^T[key][query]
    f32x4 sA00 = {0.f,0.f,0.f,0.f}, sA01 = {0.f,0.f,0.f,0.f};
    f32x4 sA10 = {0.f,0.f,0.f,0.f}, sA11 = {0.f,0.f,0.f,0.f};
    f32x4 sB00 = {0.f,0.f,0.f,0.f}, sB01 = {0.f,0.f,0.f,0.f};
    f32x4 sB10 = {0.f,0.f,0.f,0.f}, sB11 = {0.f,0.f,0.f,0.f};
    __builtin_amdgcn_s_setprio(1);
    if (do0) {
      sA00 = __builtin_amdgcn_mfma_f32_16x16x32_bf16(k0, qA0, sA00, 0, 0, 0);
      sA01 = __builtin_amdgcn_mfma_f32_16x16x32_bf16(k0, qA1, sA01, 0, 0, 0);
      sA10 = __builtin_amdgcn_mfma_f32_16x16x32_bf16(k1, qA0, sA10, 0, 0, 0);
      sA11 = __builtin_amdgcn_mfma_f32_16x16x32_bf16(k1, qA1, sA11, 0, 0, 0);
    }
    sB00 = __builtin_amdgcn_mfma_f32_16x16x32_bf16(k0, qB0, sB00, 0, 0, 0);
    sB01 = __builtin_amdgcn_mfma_f32_16x16x32_bf16(k0, qB1, sB01, 0, 0, 0);
    sB10 = __builtin_amdgcn_mfma_f32_16x16x32_bf16(k1, qB0, sB10, 0, 0, 0);
    sB11 = __builtin_amdgcn_mfma_f32_16x16x32_bf16(k1, qB1, sB11, 0, 0, 0);
    __builtin_amdgcn_s_setprio(0);

    // V loads after S-MFMAs: first use is PV
    const bf16x8 v0 = *(const bf16x8*)(VTbh + (long)lr * T_ + kb + quad * 8);
    const bf16x8 v1 = *(const bf16x8*)(VTbh + (long)(16 + lr) * T_ + kb + quad * 8);

    if (t == d0) {       // diagonal for group A
#pragma unroll
      for (int r = 0; r < 4; ++r) {
        if (mq + r > lr) { sA00[r] = -1e30f; sA11[r] = -1e30f; }
        sA10[r] = -1e30f;
      }
    }
    if (t == d1) {       // diagonal for group B
#pragma unroll
      for (int r = 0; r < 4; ++r) {
        if (mq + r > lr) { sB00[r] = -1e30f; sB11[r] = -1e30f; }
        sB10[r] = -1e30f;
      }
    }
    if (do0) {
#pragma unroll
      for (int r = 0; r < 4; ++r) {
        sA00[r] = fexp2(sA00[r]); sA01[r] = fexp2(sA01[r]);
        sA10[r] = fexp2(sA10[r]); sA11[r] = fexp2(sA11[r]);
      }
    }
#pragma unroll
    for (int r = 0; r < 4; ++r) {
      sB00[r] = fexp2(sB00[r]); sB01[r] = fexp2(sB01[r]);
      sB10[r] = fexp2(sB10[r]); sB11[r] = fexp2(sB11[r]);
    }

    __builtin_amdgcn_s_setprio(1);
    if (do0) {
      const bf16x8 pA0 = build_frag(sA00, sA10);
      const bf16x8 pA1 = build_frag(sA01, sA11);
      oA00 = __builtin_amdgcn_mfma_f32_16x16x32_bf16(pA0, v0, oA00, 0, 0, 0);
      oA01 = __builtin_amdgcn_mfma_f32_16x16x32_bf16(pA0, v1, oA01, 0, 0, 0);
      oA10 = __builtin_amdgcn_mfma_f32_16x16x32_bf16(pA1, v0, oA10, 0, 0, 0);
      oA11 = __builtin_amdgcn_mfma_f32_16x16x32_bf16(pA1, v1, oA11, 0, 0, 0);
    }
    {
      const bf16x8 pB0 = build_frag(sB00, sB10);
      const bf16x8 pB1 = build_frag(sB01, sB11);
      oB00 = __builtin_amdgcn_mfma_f32_16x16x32_bf16(pB0, v0, oB00, 0, 0, 0);
      oB01 = __builtin_amdgcn_mfma_f32_16x16x32_bf16(pB0, v1, oB01, 0, 0, 0);
      oB10 = __builtin_amdgcn_mfma_f32_16x16x32_bf16(pB1, v0, oB10, 0, 0, 0);
      oB11 = __builtin_amdgcn_mfma_f32_16x16x32_bf16(pB1, v1, oB11, 0, 0, 0);
    }
    __builtin_amdgcn_s_setprio(0);
  }

  // ---- two-pass merge: partials are additive (no-max softmax) ----
  const int b = bh / H_, h = bh - b * H_;

  // pass A: queries q0 .. q0+31
  __syncthreads();
  {
    float* my = smem + (wv * 64 + lane) * 17;     // stride 17: conflict-free
#pragma unroll
    for (int j = 0; j < 4; ++j) {
      my[j]      = oA00[j];
      my[4 + j]  = oA01[j];
      my[8 + j]  = oA10[j];
      my[12 + j] = oA11[j];
    }
  }
  __syncthreads();
  if (wv == 0) {
    float tot[16];
#pragma unroll
    for (int j = 0; j < 16; ++j)
      tot[j] = smem[lane * 17 + j] + smem[(64 + lane) * 17 + j] +
               smem[(128 + lane) * 17 + j] + smem[(192 + lane) * 17 + j];
#pragma unroll
    for (int r = 0; r < 4; ++r) {
      const float rl0 = 1.f / __shfl(tot[4 + r],  (lane & 48) + 5, 64);
      const float rl1 = 1.f / __shfl(tot[12 + r], (lane & 48) + 5, 64);
      const int qA = q0 + mq + r, qB2 = qA + 16;
      bf16_t* opA = ATTp + (long)(b * T_ + qA) * KP_ + h * D_;
      bf16_t* opB = ATTp + (long)(b * T_ + qB2) * KP_ + h * D_;
      opA[lr] = (bf16_t)(tot[r] * rl0);
      opB[lr] = (bf16_t)(tot[8 + r] * rl1);
      if (lr < 5) {
        opA[16 + lr] = (bf16_t)(tot[4 + r] * rl0);
        opB[16 + lr] = (bf16_t)(tot[12 + r] * rl1);
      }
    }
  }

  // pass B: queries q0+32 .. q0+63
  __syncthreads();
  {
    float* my = smem + (wv * 64 + lane) * 17;
#pragma unroll
    for (int j = 0; j < 4; ++j) {
      my[j]      = oB00[j];
      my[4 + j]  = oB01[j];
      my[8 + j]  = oB10[j];
      my[12 + j] = oB11[j];
    }
  }
  __syncthreads();
  if (wv == 0) {
    float tot[16];
#pragma unroll
    for (int j = 0; j < 16; ++j)
      tot[j] = smem[lane * 17 + j] + smem[(64 + lane) * 17 + j] +
               smem[(128 + lane) * 17 + j] + smem[(192 + lane) * 17 + j];
#pragma unroll
    for (int r = 0; r < 4; ++r) {
      const float rl0 = 1.f / __shfl(tot[4 + r],  (lane & 48) + 5, 64);
      const float rl1 = 1.f / __shfl(tot[12 + r], (lane & 48) + 5, 64);
      const int qA = q0 + 32 + mq + r, qB2 = qA + 16;
      bf16_t* opA = ATTp + (long)(b * T_ + qA) * KP_ + h * D_;
      bf16_t* opB = ATTp + (long)(b * T_ + qB2) * KP_ + h * D_;
      opA[lr] = (bf16_t)(tot[r] * rl0);
      opB[lr] = (bf16_t)(tot[8 + r] * rl1);
      if (lr < 5) {
        opA[16 + lr] = (bf16_t)(tot[4 + r] * rl0);
        opB[16 + lr] = (bf16_t)(tot[12 + r] * rl1);
      }
    }
  }
}

// ------------- out = ATT @ w_proj via MFMA, 32 rows/block -----------------
__global__ __launch_bounds__(256) void proj_mfma(
    const void* __restrict__ x, const bf16_t* __restrict__ ATTp,
    const bf16_t* __restrict__ WT, void* __restrict__ out) {
  __shared__ int sflag;
  probe_dtype(x, threadIdx.x, &sflag);
  const int isbf = sflag;

  const int m0 = blockIdx.x * 32;
  const int tid = threadIdx.x;
  const int wv = tid >> 6, lane = tid & 63;
  const int lr = lane & 15, quad = lane >> 4;

  const bf16x8* apU = (const bf16x8*)(ATTp + (long)(m0 + lr) * KP_ + quad * 8);
  const bf16x8* apL = (const bf16x8*)(ATTp + (long)(m0 + 16 + lr) * KP_ + quad * 8);
  const bf16x8 aU0 = apU[0], aU1 = apU[4], aU2 = apU[8], aU3 = apU[12];
  const bf16x8 aL0 = apL[0], aL1 = apL[4], aL2 = apL[8], aL3 = apL[12];

  for (int nt = wv; nt < 8; nt += 4) {
    const int n0 = nt * 16;
    const bf16x8* bp = (const bf16x8*)(WT + (long)(n0 + lr) * KP_ + quad * 8);
    const bf16x8 b0 = bp[0], b1 = bp[4], b2 = bp[8], b3 = bp[12];
    f32x4 accU = {0.f, 0.f, 0.f, 0.f};
    f32x4 accL = {0.f, 0.f, 0.f, 0.f};
    accU = __builtin_amdgcn_mfma_f32_16x16x32_bf16(aU0, b0, accU, 0, 0, 0);
    accU = __builtin_amdgcn_mfma_f32_16x16x32_bf16(aU1, b1, accU, 0, 0, 0);
    accU = __builtin_amdgcn_mfma_f32_16x16x32_bf16(aU2, b2, accU, 0, 0, 0);
    accU = __builtin_amdgcn_mfma_f32_16x16x32_bf16(aU3, b3, accU, 0, 0, 0);
    accL = __builtin_amdgcn_mfma_f32_16x16x32_bf16(aL0, b0, accL, 0, 0, 0);
    accL = __builtin_amdgcn_mfma_f32_16x16x32_bf16(aL1, b1, accL, 0, 0, 0);
    accL = __builtin_amdgcn_mfma_f32_16x16x32_bf16(aL2, b2, accL, 0, 0, 0);
    accL = __builtin_amdgcn_mfma_f32_16x16x32_bf16(aL3, b3, accL, 0, 0, 0);

    const int c = n0 + lr;
    if (c < C_) {
#pragma unroll
      for (int r = 0; r < 4; ++r) {
        const int mU = m0 + quad * 4 + r;
        const int mL = mU + 16;
        if (isbf) {
          stf((bf16*)out,  (long)mU * C_ + c, accU[r]);
          stf((bf16*)out,  (long)mL * C_ + c, accL[r]);
        } else {
          stf((float*)out, (long)mU * C_ + c, accU[r]);
          stf((float*)out, (long)mL * C_ + c, accL[r]);
        }
      }
    }
  }
}

extern "C" void kernel_launch(void* const* d_in, const int* in_sizes, int n_in,
                              void* d_out, int out_size, void* d_ws, size_t ws_size,
                              hipStream_t stream) {
  const void* x      = d_in[0];
  const void* w_attn = d_in[1];
  const void* w_proj = d_in[2];

  char* base = (char*)d_ws;
  const long QKV = (long)48 * T_ * DP_;                    // 3,145,728 bf16 each
  bf16_t* Qb = (bf16_t*)(base + 256);
  bf16_t* Kb = Qb + QKV;
  bf16_t* VT = Kb + QKV;                                   // [bh][32][T]
  bf16_t* WTa  = VT + QKV;                                 // 384*128
  bf16_t* WTp  = WTa + 384 * KP_;                          // 128*128
  bf16_t* ATTp = WTp + KP_ * KP_;                          // 16384*128

  prep_w_kernel<<<256, 256, 0, stream>>>(x, w_attn, w_proj, WTa, WTp);
  qkv_mfma<<<M_ / 32, 256, 0, stream>>>(x, WTa, Qb, Kb, VT);
  attn_mfma<<<dim3(48, 32), 256, 0, stream>>>(Qb, Kb, VT, ATTp);
  proj_mfma<<<M_ / 32, 256, 0, stream>>>(x, ATTp, WTp, d_out);
}